// Round 18
// baseline (403.889 us; speedup 1.0000x reference)
//
#include <hip/hip_runtime.h>
#include <hip/hip_bf16.h>

#define B_ 2
#define S_ 2048
#define D_ 1024
#define H_ 16
#define HD_ 64
#define KDIM 1024
#define QKVW 3072

typedef __attribute__((ext_vector_type(8))) short s16x8;
typedef __attribute__((ext_vector_type(8))) __bf16 bf16x8;
typedef __attribute__((ext_vector_type(4))) float f32x4;
typedef __attribute__((ext_vector_type(16))) float f32x16;
typedef __attribute__((ext_vector_type(4))) unsigned short u16x4;

__device__ __forceinline__ unsigned short f2bf(float f) {
  union { __bf16 b; unsigned short u; } v;
  v.b = (__bf16)f;
  return v.u;
}

__device__ __forceinline__ unsigned pk2(float lo, float hi) {
  union { unsigned short s[2]; unsigned u; } r;
  r.s[0] = f2bf(lo); r.s[1] = f2bf(hi);
  return r.u;
}

// permlane32_swap(a, b): HW swaps a[32+j] <-> b[j].
__device__ __forceinline__ void plswap2(unsigned& a_out, unsigned& b_out,
                                        unsigned a, unsigned b) {
  auto rr = __builtin_amdgcn_permlane32_swap(a, b, false, false);
  unsigned out[2];
  __builtin_memcpy(out, &rr, 8);
  a_out = out[0];
  b_out = out[1];
}

#define MFMA16(a, b, c) __builtin_amdgcn_mfma_f32_16x16x32_bf16((a), (b), (c), 0, 0, 0)
#define MFMA32(a, b, c) __builtin_amdgcn_mfma_f32_32x32x16_bf16((a), (b), (c), 0, 0, 0)

// fenced barrier: s_barrier with compiler memory clobber (no waitcnt emitted).
// Raw __builtin_amdgcn_s_barrier is IntrNoMem -> LDS ops may be reordered across
// it; fatal for single-buffered LDS reuse (r17 race).
#define SBAR() __asm__ volatile("s_barrier" ::: "memory")

__device__ __forceinline__ void gll16(const void* g, void* l) {
  __builtin_amdgcn_global_load_lds(
      (const __attribute__((address_space(1))) void*)g,
      (__attribute__((address_space(3))) void*)l, 16, 0, 0);
}

// ---------------- fused prep: X fp32->bf16 | w_qkv transpose | w_out transpose
__global__ __launch_bounds__(256) void prep(const float* __restrict__ X,
                                            unsigned short* __restrict__ Xb,
                                            const float* __restrict__ Wq,
                                            unsigned short* __restrict__ WqT,
                                            const float* __restrict__ Wo,
                                            unsigned short* __restrict__ WoT) {
  const int bid = blockIdx.x;
  const int t = threadIdx.x;
  if (bid < 2048) {
    const int i = (bid * 256 + t) * 8;
    const float4 a = *reinterpret_cast<const float4*>(X + i);
    const float4 b = *reinterpret_cast<const float4*>(X + i + 4);
    u16x4 lo = {f2bf(a.x), f2bf(a.y), f2bf(a.z), f2bf(a.w)};
    u16x4 hi = {f2bf(b.x), f2bf(b.y), f2bf(b.z), f2bf(b.w)};
    *reinterpret_cast<u16x4*>(Xb + i) = lo;
    *reinterpret_cast<u16x4*>(Xb + i + 4) = hi;
    return;
  }
  __shared__ float T[64][65];
  const float* W;
  unsigned short* Wt;
  int N, k0, n0;
  if (bid < 2048 + 768) {
    const int i = bid - 2048;
    W = Wq; Wt = WqT; N = 3072;
    n0 = (i % 48) * 64; k0 = (i / 48) * 64;
  } else {
    const int i = bid - 2816;
    W = Wo; Wt = WoT; N = 1024;
    n0 = (i % 16) * 64; k0 = (i / 16) * 64;
  }
  const int lr = t >> 4, lc = (t & 15) * 4;
#pragma unroll
  for (int p = 0; p < 4; ++p) {
    const int r = lr + p * 16;
    const float4 v = *reinterpret_cast<const float4*>(W + (size_t)(k0 + r) * N + n0 + lc);
    T[r][lc + 0] = v.x; T[r][lc + 1] = v.y; T[r][lc + 2] = v.z; T[r][lc + 3] = v.w;
  }
  __syncthreads();
  const int wn = t >> 4, wk = (t & 15) * 4;
#pragma unroll
  for (int p = 0; p < 4; ++p) {
    const int n = wn + p * 16;
    u16x4 o = {f2bf(T[wk + 0][n]), f2bf(T[wk + 1][n]), f2bf(T[wk + 2][n]), f2bf(T[wk + 3][n])};
    *reinterpret_cast<u16x4*>(Wt + (size_t)(n0 + n) * 1024 + k0 + wk) = o;
  }
}

// ---------------- QKV projection: 64x128 tile, dbuf LDS (48KB -> 3 blk/CU),
// counted vmcnt, 2D XCD chunks (16m x 12n per XCD).
// Q/K columns -> Cq; V columns -> Vt[b,h,hd,s] directly (LDS-transposed epilogue).
__global__ __launch_bounds__(256) void gemm_qkv(
    const unsigned short* __restrict__ Xb, const unsigned short* __restrict__ WT,
    const float* __restrict__ bias, unsigned short* __restrict__ Cq,
    unsigned short* __restrict__ Vt) {
  __shared__ __align__(16) unsigned short As[2][64 * 64];
  __shared__ __align__(16) unsigned short Bs[2][128 * 64];
  const int bid = blockIdx.y * 24 + blockIdx.x;          // 1536 blocks
  const int xcd = bid & 7, rr = bid >> 3;                // rr 0..191
  const int m0 = ((xcd >> 1) * 16 + (rr & 15)) * 64;     // 4 m-groups of 16 panels
  const int n0 = ((xcd & 1) * 12 + (rr >> 4)) * 128;     // 2 n-groups of 12 panels
  const int t = threadIdx.x;
  const int lane = t & 63, wid = t >> 6;
  const int wr = wid >> 1, wc = wid & 1;
  const int l15 = lane & 15, l16 = lane >> 4;
  const int srow = lane >> 3, scol = ((lane & 7) ^ srow) << 3;
  f32x4 acc[2][4] = {};

#define GSTAGE(buf, k0)                                                              \
  do {                                                                               \
    _Pragma("unroll") for (int c = 0; c < 2; ++c) {                                  \
      const int r8 = wid * 16 + c * 8;                                               \
      gll16(Xb + (size_t)(m0 + r8 + srow) * KDIM + (k0) + scol, &As[buf][r8 * 64]);  \
    }                                                                                \
    _Pragma("unroll") for (int c = 0; c < 4; ++c) {                                  \
      const int r8 = wid * 32 + c * 8;                                               \
      gll16(WT + (size_t)(n0 + r8 + srow) * KDIM + (k0) + scol, &Bs[buf][r8 * 64]);  \
    }                                                                                \
  } while (0)

  GSTAGE(0, 0);
  for (int kt = 0; kt < 16; ++kt) {
    const int cur = kt & 1;
    if (kt + 1 < 16) {
      GSTAGE(cur ^ 1, (kt + 1) * 64);
      __asm__ volatile("s_waitcnt vmcnt(6)" ::: "memory");  // tile kt landed; kt+1 in flight
    } else {
      __asm__ volatile("s_waitcnt vmcnt(0)" ::: "memory");
    }
    SBAR();
    const int key = (l15 & 7) << 4;
    const char* ab = (const char*)&As[cur][0] + (wr * 32 + l15) * 128;
    const char* bb = (const char*)&Bs[cur][0] + (wc * 64 + l15) * 128;
#pragma unroll
    for (int ks = 0; ks < 2; ++ks) {
      bf16x8 af[2], bfr[4];
#pragma unroll
      for (int m = 0; m < 2; ++m)
        af[m] = *(const bf16x8*)(ab + m * 2048 + ((ks * 64 + l16 * 16) ^ key));
#pragma unroll
      for (int n = 0; n < 4; ++n)
        bfr[n] = *(const bf16x8*)(bb + n * 2048 + ((ks * 64 + l16 * 16) ^ key));
#pragma unroll
      for (int m = 0; m < 2; ++m)
#pragma unroll
        for (int n = 0; n < 4; ++n)
          acc[m][n] = MFMA16(af[m], bfr[n], acc[m][n]);
    }
    SBAR();
  }
  if (n0 < 2048) {
    // Q/K columns -> plain Cq (+bias)
#pragma unroll
    for (int n = 0; n < 4; ++n) {
      const int col = n0 + wc * 64 + n * 16 + l15;
      const float bv = bias[col];
#pragma unroll
      for (int m = 0; m < 2; ++m) {
#pragma unroll
        for (int j = 0; j < 4; ++j) {
          const int row = m0 + wr * 32 + m * 16 + l16 * 4 + j;
          Cq[(size_t)row * QKVW + col] = f2bf(acc[m][n][j] + bv);
        }
      }
    }
  } else {
    // V columns -> Vt[b,h,hd,s] via LDS transpose (Bs free after final barrier)
    unsigned short* T = &Bs[0][0];  // [128][68] u16 = 17408 B
#pragma unroll
    for (int n = 0; n < 4; ++n) {
      const int col = n0 + wc * 64 + n * 16 + l15;
      const float bv = bias[col];
      const int trow = wc * 64 + n * 16 + l15;
#pragma unroll
      for (int m = 0; m < 2; ++m) {
#pragma unroll
        for (int j = 0; j < 4; ++j)
          T[trow * 68 + wr * 32 + m * 16 + l16 * 4 + j] = f2bf(acc[m][n][j] + bv);
      }
    }
    __syncthreads();
    const int bb2 = m0 >> 11, s0t = m0 & 2047;
    const int hh0 = (n0 - 2048) >> 6;
#pragma unroll
    for (int p = 0; p < 4; ++p) {
      const int idx = p * 256 + t;
      const int vd = idx >> 3, sg = (idx & 7) * 8;
      const int hd = vd & 63, hx = vd >> 6;
      *reinterpret_cast<s16x8*>(
          &Vt[(((size_t)bb2 * H_ + hh0 + hx) * HD_ + hd) * S_ + s0t + sg]) =
          *reinterpret_cast<const s16x8*>(&T[vd * 68 + sg]);
    }
  }
}

// ---------------- Flash attention: 4-wave blocks, K AND V single-buffered
// (restage-after-use, deferred waits), 32KB LDS -> 5 blocks/CU.
// ALL loop barriers are fenced (SBAR) to pin LDS ops at compile time.
__global__ __launch_bounds__(256, 5) void attn(
    const unsigned short* __restrict__ QKVc, const unsigned short* __restrict__ Vt,
    unsigned short* __restrict__ Cxt) {
  __shared__ __align__(16) unsigned short Kl[2][4096];  // [parity][kv64*hd64] 16KB
  __shared__ __align__(16) unsigned short Vl[2][4096];  // [parity][hd64*kv64] 16KB
  const int bi = blockIdx.x;
  const int xcd = bi & 7, slot = bi >> 3;
  const int bh = xcd * 4 + (slot & 3);
  const int qt = 31 - (slot >> 2);           // 64-row supertile, heavy first
  const int t = threadIdx.x, lane = t & 63, wid = t >> 6;
  const int qw = wid & 1, pw = wid >> 1;     // q-half / staging role, kv-parity
  const int l31 = lane & 31, h = lane >> 5;
  const int h8 = h * 8, h16 = h * 16, h4 = h * 4;
  const int bb = bh >> 4, hh = bh & 15;
  const size_t base = (size_t)bh * (S_ * HD_);
  const int q0 = qt * 64 + qw * 32;          // this wave's 32 q-rows
  const float NEG = -1e30f;
  const float SCALE = 0.18033688011112042f;  // (1/8)*log2(e)
  const float FM = 10.0f;                    // fixed softmax exponent (exp2 domain)
  const int srow = lane >> 3;
  const int scol = ((lane & 7) ^ srow) << 3;

  bf16x8 qf[4];
  {
    const unsigned short* qp =
        QKVc + (size_t)(bb * S_ + q0 + l31) * QKVW + hh * 64 + h8;
#pragma unroll
    for (int ks = 0; ks < 4; ++ks) qf[ks] = *reinterpret_cast<const bf16x8*>(qp + ks * 16);
  }
  f32x16 o0 = {}, o1 = {};
  float lacc[8] = {};

#define STAGEK(kvb)                                                                   \
  do {                                                                                \
    _Pragma("unroll") for (int c = 0; c < 8; ++c)                                     \
      gll16(QKVc + (size_t)(bb * S_ + (kvb) + c * 8 + srow) * QKVW + 1024 +           \
                hh * 64 + scol,                                                       \
            &Kl[pw][c * 8 * 64]);                                                     \
  } while (0)

#define STAGEV(kvb)                                                                   \
  do {                                                                                \
    _Pragma("unroll") for (int c = 0; c < 8; ++c)                                     \
      gll16(Vt + base + (size_t)(c * 8 + srow) * S_ + (kvb) + scol,                   \
            &Vl[pw][c * 8 * 64]);                                                     \
  } while (0)

#define COMPUTE_QK(tcur)                                                             \
  do {                                                                               \
    const int kv0 = (tcur) * 64;                                                     \
    const bool diag = (kv0 + 63 > q0);                                               \
    const char* kbase = (const char*)&Kl[pw][0];                                     \
    const int key = (l31 & 7) << 4;                                                  \
    f32x16 s0 = {}, s1 = {};                                                         \
    __builtin_amdgcn_s_setprio(1);                                                   \
    _Pragma("unroll") for (int ks = 0; ks < 4; ++ks) {                               \
      bf16x8 ka = *(const bf16x8*)(kbase + l31 * 128 + ((ks * 32 + h16) ^ key));     \
      s0 = MFMA32(ka, qf[ks], s0);                                                   \
    }                                                                                \
    if (f2) {                                                                        \
      _Pragma("unroll") for (int ks = 0; ks < 4; ++ks) {                             \
        bf16x8 kb = *(const bf16x8*)(kbase + (32 + l31) * 128 + ((ks * 32 + h16) ^ key)); \
        s1 = MFMA32(kb, qf[ks], s1);                                                 \
      }                                                                              \
    }                                                                                \
    __builtin_amdgcn_s_setprio(0);                                                   \
    if (diag) {                                                                      \
      const int lim0 = q0 + l31 - kv0;                                               \
      const int lim1 = lim0 - 32;                                                    \
      _Pragma("unroll") for (int r = 0; r < 16; ++r) {                               \
        const int cr = (r & 3) + 8 * (r >> 2) + h4;                                  \
        if (cr > lim0) s0[r] = NEG;                                                  \
        if (f2 && cr > lim1) s1[r] = NEG;                                            \
      }                                                                              \
    }                                                                                \
    _Pragma("unroll") for (int r = 0; r < 16; ++r)                                   \
      s0[r] = exp2f(fmaf(s0[r], SCALE, -FM));                                        \
    if (f2) {                                                                        \
      _Pragma("unroll") for (int r = 0; r < 16; ++r)                                 \
        s1[r] = exp2f(fmaf(s1[r], SCALE, -FM));                                      \
    }                                                                                \
    _Pragma("unroll") for (int r = 0; r < 8; ++r) {                                  \
      float ps = s0[r] + s0[r + 8];                                                  \
      if (f2) ps += s1[r] + s1[r + 8];                                               \
      lacc[r] += ps;                                                                 \
    }                                                                                \
    {                                                                                \
      union { unsigned u[4]; bf16x8 v; } uu;                                         \
      unsigned a0, a1, a2, a3, w0, w1, w2, w3;                                       \
      w0 = pk2(s0[0], s0[1]); w1 = pk2(s0[2], s0[3]);                                \
      w2 = pk2(s0[4], s0[5]); w3 = pk2(s0[6], s0[7]);                                \
      plswap2(a0, a2, w0, w2); plswap2(a1, a3, w1, w3);                              \
      uu.u[0] = a0; uu.u[1] = a1; uu.u[2] = a2; uu.u[3] = a3; pa[0] = uu.v;          \
      w0 = pk2(s0[8], s0[9]); w1 = pk2(s0[10], s0[11]);                              \
      w2 = pk2(s0[12], s0[13]); w3 = pk2(s0[14], s0[15]);                            \
      plswap2(a0, a2, w0, w2); plswap2(a1, a3, w1, w3);                              \
      uu.u[0] = a0; uu.u[1] = a1; uu.u[2] = a2; uu.u[3] = a3; pa[1] = uu.v;          \
      if (f2) {                                                                      \
        w0 = pk2(s1[0], s1[1]); w1 = pk2(s1[2], s1[3]);                              \
        w2 = pk2(s1[4], s1[5]); w3 = pk2(s1[6], s1[7]);                              \
        plswap2(a0, a2, w0, w2); plswap2(a1, a3, w1, w3);                            \
        uu.u[0] = a0; uu.u[1] = a1; uu.u[2] = a2; uu.u[3] = a3; pa[2] = uu.v;        \
        w0 = pk2(s1[8], s1[9]); w1 = pk2(s1[10], s1[11]);                            \
        w2 = pk2(s1[12], s1[13]); w3 = pk2(s1[14], s1[15]);                          \
        plswap2(a0, a2, w0, w2); plswap2(a1, a3, w1, w3);                            \
        uu.u[0] = a0; uu.u[1] = a1; uu.u[2] = a2; uu.u[3] = a3; pa[3] = uu.v;        \
      }                                                                              \
    }                                                                                \
  } while (0)

#define COMPUTE_PV()                                                                 \
  do {                                                                               \
    const char* vbase = (const char*)&Vl[pw][0];                                     \
    const int key = (l31 & 7) << 4;                                                  \
    __builtin_amdgcn_s_setprio(1);                                                   \
    _Pragma("unroll") for (int hb = 0; hb < 2; ++hb) {                               \
      _Pragma("unroll") for (int ks = 0; ks < 4; ++ks)                               \
        if (f2 || ks < 2) {                                                          \
          bf16x8 va = *(const bf16x8*)(vbase + (hb * 32 + l31) * 128 +               \
                                       ((ks * 32 + h16) ^ key));                     \
          if (hb == 0) o0 = MFMA32(va, pa[ks], o0);                                  \
          else         o1 = MFMA32(va, pa[ks], o1);                                  \
        }                                                                            \
    }                                                                                \
    __builtin_amdgcn_s_setprio(0);                                                   \
  } while (0)

  const int npair = (qt >> 1) + 1;
  // prologue: K-stagers load the pair-0 K tile for their parity
  if (qw == 0) STAGEK(pw * 64);   // kvb <= 64 always in-bounds
  for (int p = 0; p < npair; ++p) {
    const int tcur = 2 * p + pw;
    const bool active = (tcur <= qt);
    if (qw == 0) __asm__ volatile("s_waitcnt vmcnt(0)" ::: "memory");  // K(t) landed
    SBAR();                                       // K(t) visible; Vl[pw] free (PV(t-2) done)
    if (qw == 1 && active) STAGEV(tcur * 64);     // V(t): consumed after QK -> hides
    bf16x8 pa[4];
    const bool f2 = (tcur * 64 + 32 <= q0 + 31);
    if (active) COMPUTE_QK(tcur);
    SBAR();                                       // all waves done reading Kl[pw]
    if (qw == 0 && tcur + 2 <= qt) STAGEK((tcur + 2) * 64);  // restage same buffer
    if (qw == 1) __asm__ volatile("s_waitcnt vmcnt(0)" ::: "memory");  // V(t) landed
    SBAR();                                       // V(t) visible
    if (active) COMPUTE_PV();
    // next iteration's first barrier separates PV(t) readers from STAGEV(t+2)
  }

  // ---- row sums: tree + cross-half, once
  float lrow = 0.f;
#pragma unroll
  for (int r = 0; r < 8; ++r) lrow += lacc[r];
  lrow += __shfl_xor(lrow, 32);

  // ---- parity merge via LDS, two phases (Kl = 16KB scratch)
  float* mb = (float*)&Kl[0][0];
  const int miA = (qw * 64 + lane) * 17;
  __syncthreads();                               // all compute done; Kl free
  if (pw == 1) {
#pragma unroll
    for (int r = 0; r < 16; ++r) mb[miA + r] = o0[r];
    mb[miA + 16] = lrow;
  }
  __syncthreads();
  if (pw == 0) {
#pragma unroll
    for (int r = 0; r < 16; ++r) o0[r] += mb[miA + r];
    lrow += mb[miA + 16];
  }
  __syncthreads();
  const int miB = (qw * 64 + lane) * 16;
  if (pw == 1) {
#pragma unroll
    for (int r = 0; r < 16; ++r) mb[miB + r] = o1[r];
  }
  __syncthreads();
  if (pw == 1) return;
#pragma unroll
  for (int r = 0; r < 16; ++r) o1[r] += mb[miB + r];

  // ---- epilogue: O^T -> LDS (Vl) -> coalesced bf16 stores (Cxt [b,h,s,hd])
  float* obuf = (float*)&Vl[0][0] + (size_t)qw * 2048;
  const float rl = 1.0f / lrow;
#pragma unroll
  for (int r = 0; r < 16; ++r) {
    const int cr = (r & 3) + 8 * (r >> 2) + h4;
    obuf[l31 * 64 + (cr ^ ((l31 & 7) << 2))] = o0[r] * rl;
    obuf[l31 * 64 + ((32 + cr) ^ ((l31 & 7) << 2))] = o1[r] * rl;
  }
  __asm__ volatile("s_waitcnt lgkmcnt(0)" ::: "memory");
#pragma unroll
  for (int p = 0; p < 8; ++p) {
    const int r = (lane >> 4) + p * 4;
    const int ce = ((lane & 15) * 4) ^ ((r & 7) << 2);
    const f32x4 v = *reinterpret_cast<const f32x4*>(&obuf[r * 64 + ce]);
    u16x4 wv = {f2bf(v[0]), f2bf(v[1]), f2bf(v[2]), f2bf(v[3])};
    *reinterpret_cast<u16x4*>(&Cxt[base + (size_t)(q0 + r) * HD_ + (lane & 15) * 4]) = wv;
  }
}

// ---------------- Output projection: 64x128 tile, dbuf LDS (48KB -> 3 blk/CU),
// counted vmcnt, 2D XCD chunks (16m x 4n per XCD). Ctx head-blocked [b][h][s][hd].
__global__ __launch_bounds__(256) void gemm_out(
    const unsigned short* __restrict__ Cxt, const unsigned short* __restrict__ WT,
    const float* __restrict__ bias, float* __restrict__ out) {
  constexpr int NM = 1024;
  __shared__ __align__(16) unsigned short As[2][64 * 64];
  __shared__ __align__(16) unsigned short Bs[2][128 * 64];
  const int bid = blockIdx.y * 8 + blockIdx.x;           // 512 blocks
  const int xcd = bid & 7, rr = bid >> 3;                // rr 0..63
  const int m0 = ((xcd >> 1) * 16 + (rr & 15)) * 64;     // 4 m-groups of 16 panels
  const int n0 = ((xcd & 1) * 4 + (rr >> 4)) * 128;      // 2 n-groups of 4 panels
  const int t = threadIdx.x;
  const int lane = t & 63, wid = t >> 6;
  const int wr = wid >> 1, wc = wid & 1;
  const int l15 = lane & 15, l16 = lane >> 4;
  const int srow = lane >> 3, scol = ((lane & 7) ^ srow) << 3;
  f32x4 acc[2][4] = {};

#define OSTAGE(buf, k0)                                                              \
  do {                                                                               \
    const int head = (k0) >> 6;                                                      \
    _Pragma("unroll") for (int c = 0; c < 2; ++c) {                                  \
      const int r8 = wid * 16 + c * 8;                                               \
      const int gr = m0 + r8 + srow;                                                 \
      gll16(Cxt + ((((size_t)(gr >> 11) * H_ + head) << 11) + (gr & 2047)) * HD_ + scol, \
            &As[buf][r8 * 64]);                                                      \
    }                                                                                \
    _Pragma("unroll") for (int c = 0; c < 4; ++c) {                                  \
      const int r8 = wid * 32 + c * 8;                                               \
      gll16(WT + (size_t)(n0 + r8 + srow) * KDIM + (k0) + scol, &Bs[buf][r8 * 64]);  \
    }                                                                                \
  } while (0)

  OSTAGE(0, 0);
  for (int kt = 0; kt < 16; ++kt) {
    const int cur = kt & 1;
    if (kt + 1 < 16) {
      OSTAGE(cur ^ 1, (kt + 1) * 64);
      __asm__ volatile("s_waitcnt vmcnt(6)" ::: "memory");
    } else {
      __asm__ volatile("s_waitcnt vmcnt(0)" ::: "memory");
    }
    SBAR();
    const int key = (l15 & 7) << 4;
    const char* ab = (const char*)&As[cur][0] + (wr * 32 + l15) * 128;
    const char* bb = (const char*)&Bs[cur][0] + (wc * 64 + l15) * 128;
#pragma unroll
    for (int ks = 0; ks < 2; ++ks) {
      bf16x8 af[2], bfr[4];
#pragma unroll
      for (int m = 0; m < 2; ++m)
        af[m] = *(const bf16x8*)(ab + m * 2048 + ((ks * 64 + l16 * 16) ^ key));
#pragma unroll
      for (int n = 0; n < 4; ++n)
        bfr[n] = *(const bf16x8*)(bb + n * 2048 + ((ks * 64 + l16 * 16) ^ key));
#pragma unroll
      for (int m = 0; m < 2; ++m)
#pragma unroll
        for (int n = 0; n < 4; ++n)
          acc[m][n] = MFMA16(af[m], bfr[n], acc[m][n]);
    }
    SBAR();
  }
#pragma unroll
  for (int n = 0; n < 4; ++n) {
    const int col = n0 + wc * 64 + n * 16 + l15;
    const float bv = bias[col];
#pragma unroll
    for (int m = 0; m < 2; ++m) {
#pragma unroll
      for (int j = 0; j < 4; ++j) {
        const int row = m0 + wr * 32 + m * 16 + l16 * 4 + j;
        out[(size_t)row * NM + col] = acc[m][n][j] + bv;
      }
    }
  }
}

extern "C" void kernel_launch(void* const* d_in, const int* in_sizes, int n_in,
                              void* d_out, int out_size, void* d_ws, size_t ws_size,
                              hipStream_t stream) {
  const float* x = (const float*)d_in[0];
  const float* w_qkv = (const float*)d_in[1];
  const float* b_qkv = (const float*)d_in[2];
  const float* w_out = (const float*)d_in[3];
  const float* b_out = (const float*)d_in[4];
  float* out = (float*)d_out;

  const size_t NTOK = (size_t)B_ * H_ * S_ * HD_;  // 4,194,304 elements
  unsigned short* QKVc = (unsigned short*)d_ws;     // [4096][3072]
  unsigned short* Vt = QKVc + (size_t)4096 * QKVW;  // V transposed [b,h,hd,s]
  unsigned short* WqT = Vt + NTOK;                  // [3072][1024]
  unsigned short* WoT = WqT + (size_t)3072 * 1024;  // [1024][1024]
  unsigned short* Xbf = WoT + (size_t)1024 * 1024;  // [4096][1024]
  unsigned short* Cxt = Xbf;                        // alias: Xbf dead before attn writes

  hipLaunchKernelGGL(prep, dim3(2048 + 768 + 256), dim3(256), 0, stream,
                     x, Xbf, w_qkv, WqT, w_out, WoT);
  hipLaunchKernelGGL(gemm_qkv, dim3(24, 64), dim3(256), 0, stream, Xbf, WqT, b_qkv, QKVc, Vt);
  hipLaunchKernelGGL(attn, dim3(1024), dim3(256), 0, stream, QKVc, Vt, Cxt);
  hipLaunchKernelGGL(gemm_out, dim3(8, 64), dim3(256), 0, stream, Cxt, WoT, b_out, out);
}

// Round 19
// 100.687 us; speedup vs baseline: 4.0113x; 4.0113x over previous
//
#include <hip/hip_runtime.h>
#include <hip/hip_bf16.h>

#define B_ 2
#define S_ 2048
#define D_ 1024
#define H_ 16
#define HD_ 64
#define KDIM 1024
#define QKVW 3072

typedef __attribute__((ext_vector_type(8))) short s16x8;
typedef __attribute__((ext_vector_type(8))) __bf16 bf16x8;
typedef __attribute__((ext_vector_type(4))) float f32x4;
typedef __attribute__((ext_vector_type(16))) float f32x16;
typedef __attribute__((ext_vector_type(4))) unsigned short u16x4;

__device__ __forceinline__ unsigned short f2bf(float f) {
  union { __bf16 b; unsigned short u; } v;
  v.b = (__bf16)f;
  return v.u;
}

__device__ __forceinline__ unsigned pk2(float lo, float hi) {
  union { unsigned short s[2]; unsigned u; } r;
  r.s[0] = f2bf(lo); r.s[1] = f2bf(hi);
  return r.u;
}

// permlane32_swap(a, b): HW swaps a[32+j] <-> b[j].
__device__ __forceinline__ void plswap2(unsigned& a_out, unsigned& b_out,
                                        unsigned a, unsigned b) {
  auto rr = __builtin_amdgcn_permlane32_swap(a, b, false, false);
  unsigned out[2];
  __builtin_memcpy(out, &rr, 8);
  a_out = out[0];
  b_out = out[1];
}

#define MFMA16(a, b, c) __builtin_amdgcn_mfma_f32_16x16x32_bf16((a), (b), (c), 0, 0, 0)
#define MFMA32(a, b, c) __builtin_amdgcn_mfma_f32_32x32x16_bf16((a), (b), (c), 0, 0, 0)

__device__ __forceinline__ void gll16(const void* g, void* l) {
  __builtin_amdgcn_global_load_lds(
      (const __attribute__((address_space(1))) void*)g,
      (__attribute__((address_space(3))) void*)l, 16, 0, 0);
}

// ---------------- fused prep: X fp32->bf16 | w_qkv transpose | w_out transpose
__global__ __launch_bounds__(256) void prep(const float* __restrict__ X,
                                            unsigned short* __restrict__ Xb,
                                            const float* __restrict__ Wq,
                                            unsigned short* __restrict__ WqT,
                                            const float* __restrict__ Wo,
                                            unsigned short* __restrict__ WoT) {
  const int bid = blockIdx.x;
  const int t = threadIdx.x;
  if (bid < 2048) {
    const int i = (bid * 256 + t) * 8;
    const float4 a = *reinterpret_cast<const float4*>(X + i);
    const float4 b = *reinterpret_cast<const float4*>(X + i + 4);
    u16x4 lo = {f2bf(a.x), f2bf(a.y), f2bf(a.z), f2bf(a.w)};
    u16x4 hi = {f2bf(b.x), f2bf(b.y), f2bf(b.z), f2bf(b.w)};
    *reinterpret_cast<u16x4*>(Xb + i) = lo;
    *reinterpret_cast<u16x4*>(Xb + i + 4) = hi;
    return;
  }
  __shared__ float T[64][65];
  const float* W;
  unsigned short* Wt;
  int N, k0, n0;
  if (bid < 2048 + 768) {
    const int i = bid - 2048;
    W = Wq; Wt = WqT; N = 3072;
    n0 = (i % 48) * 64; k0 = (i / 48) * 64;
  } else {
    const int i = bid - 2816;
    W = Wo; Wt = WoT; N = 1024;
    n0 = (i % 16) * 64; k0 = (i / 16) * 64;
  }
  const int lr = t >> 4, lc = (t & 15) * 4;
#pragma unroll
  for (int p = 0; p < 4; ++p) {
    const int r = lr + p * 16;
    const float4 v = *reinterpret_cast<const float4*>(W + (size_t)(k0 + r) * N + n0 + lc);
    T[r][lc + 0] = v.x; T[r][lc + 1] = v.y; T[r][lc + 2] = v.z; T[r][lc + 3] = v.w;
  }
  __syncthreads();
  const int wn = t >> 4, wk = (t & 15) * 4;
#pragma unroll
  for (int p = 0; p < 4; ++p) {
    const int n = wn + p * 16;
    u16x4 o = {f2bf(T[wk + 0][n]), f2bf(T[wk + 1][n]), f2bf(T[wk + 2][n]), f2bf(T[wk + 3][n])};
    *reinterpret_cast<u16x4*>(Wt + (size_t)(n0 + n) * 1024 + k0 + wk) = o;
  }
}

// ---------------- QKV projection: 64x128 tile, dbuf LDS (48KB -> 3 blk/CU),
// counted vmcnt, 2D XCD chunks (16m x 12n per XCD).
// Q/K columns -> Cq; V columns -> Vt[b,h,hd,s] directly (LDS-transposed epilogue).
__global__ __launch_bounds__(256) void gemm_qkv(
    const unsigned short* __restrict__ Xb, const unsigned short* __restrict__ WT,
    const float* __restrict__ bias, unsigned short* __restrict__ Cq,
    unsigned short* __restrict__ Vt) {
  __shared__ __align__(16) unsigned short As[2][64 * 64];
  __shared__ __align__(16) unsigned short Bs[2][128 * 64];
  const int bid = blockIdx.y * 24 + blockIdx.x;          // 1536 blocks
  const int xcd = bid & 7, rr = bid >> 3;                // rr 0..191
  const int m0 = ((xcd >> 1) * 16 + (rr & 15)) * 64;     // 4 m-groups of 16 panels
  const int n0 = ((xcd & 1) * 12 + (rr >> 4)) * 128;     // 2 n-groups of 12 panels
  const int t = threadIdx.x;
  const int lane = t & 63, wid = t >> 6;
  const int wr = wid >> 1, wc = wid & 1;
  const int l15 = lane & 15, l16 = lane >> 4;
  const int srow = lane >> 3, scol = ((lane & 7) ^ srow) << 3;
  f32x4 acc[2][4] = {};

#define GSTAGE(buf, k0)                                                              \
  do {                                                                               \
    _Pragma("unroll") for (int c = 0; c < 2; ++c) {                                  \
      const int r8 = wid * 16 + c * 8;                                               \
      gll16(Xb + (size_t)(m0 + r8 + srow) * KDIM + (k0) + scol, &As[buf][r8 * 64]);  \
    }                                                                                \
    _Pragma("unroll") for (int c = 0; c < 4; ++c) {                                  \
      const int r8 = wid * 32 + c * 8;                                               \
      gll16(WT + (size_t)(n0 + r8 + srow) * KDIM + (k0) + scol, &Bs[buf][r8 * 64]);  \
    }                                                                                \
  } while (0)

  GSTAGE(0, 0);
  for (int kt = 0; kt < 16; ++kt) {
    const int cur = kt & 1;
    if (kt + 1 < 16) {
      GSTAGE(cur ^ 1, (kt + 1) * 64);
      __asm__ volatile("s_waitcnt vmcnt(6)" ::: "memory");  // tile kt landed; kt+1 in flight
    } else {
      __asm__ volatile("s_waitcnt vmcnt(0)" ::: "memory");
    }
    __builtin_amdgcn_s_barrier();
    const int key = (l15 & 7) << 4;
    const char* ab = (const char*)&As[cur][0] + (wr * 32 + l15) * 128;
    const char* bb = (const char*)&Bs[cur][0] + (wc * 64 + l15) * 128;
#pragma unroll
    for (int ks = 0; ks < 2; ++ks) {
      bf16x8 af[2], bfr[4];
#pragma unroll
      for (int m = 0; m < 2; ++m)
        af[m] = *(const bf16x8*)(ab + m * 2048 + ((ks * 64 + l16 * 16) ^ key));
#pragma unroll
      for (int n = 0; n < 4; ++n)
        bfr[n] = *(const bf16x8*)(bb + n * 2048 + ((ks * 64 + l16 * 16) ^ key));
#pragma unroll
      for (int m = 0; m < 2; ++m)
#pragma unroll
        for (int n = 0; n < 4; ++n)
          acc[m][n] = MFMA16(af[m], bfr[n], acc[m][n]);
    }
    __builtin_amdgcn_s_barrier();
  }
  if (n0 < 2048) {
    // Q/K columns -> plain Cq (+bias)
#pragma unroll
    for (int n = 0; n < 4; ++n) {
      const int col = n0 + wc * 64 + n * 16 + l15;
      const float bv = bias[col];
#pragma unroll
      for (int m = 0; m < 2; ++m) {
#pragma unroll
        for (int j = 0; j < 4; ++j) {
          const int row = m0 + wr * 32 + m * 16 + l16 * 4 + j;
          Cq[(size_t)row * QKVW + col] = f2bf(acc[m][n][j] + bv);
        }
      }
    }
  } else {
    // V columns -> Vt[b,h,hd,s] via LDS transpose (Bs free after final barrier)
    unsigned short* T = &Bs[0][0];  // [128][68] u16 = 17408 B
#pragma unroll
    for (int n = 0; n < 4; ++n) {
      const int col = n0 + wc * 64 + n * 16 + l15;
      const float bv = bias[col];
      const int trow = wc * 64 + n * 16 + l15;
#pragma unroll
      for (int m = 0; m < 2; ++m) {
#pragma unroll
        for (int j = 0; j < 4; ++j)
          T[trow * 68 + wr * 32 + m * 16 + l16 * 4 + j] = f2bf(acc[m][n][j] + bv);
      }
    }
    __syncthreads();
    const int bb2 = m0 >> 11, s0t = m0 & 2047;
    const int hh0 = (n0 - 2048) >> 6;
#pragma unroll
    for (int p = 0; p < 4; ++p) {
      const int idx = p * 256 + t;
      const int vd = idx >> 3, sg = (idx & 7) * 8;
      const int hd = vd & 63, hx = vd >> 6;
      *reinterpret_cast<s16x8*>(
          &Vt[(((size_t)bb2 * H_ + hh0 + hx) * HD_ + hd) * S_ + s0t + sg]) =
          *reinterpret_cast<const s16x8*>(&T[vd * 68 + sg]);
    }
  }
}

// ---------------- Flash attention: [r12/r16-proven 47us] 4-wave blocks,
// K dbuf + V single, fixed-exponent softmax, counted vmcnt.
// 1024 blocks, 4 heads/XCD, heavy-first.
__global__ __launch_bounds__(256, 3) void attn(
    const unsigned short* __restrict__ QKVc, const unsigned short* __restrict__ Vt,
    unsigned short* __restrict__ Cxt) {
  __shared__ __align__(16) unsigned short Kl[2][2][4096];  // [Kdbuf][parity][kv64*hd64] 32KB
  __shared__ __align__(16) unsigned short Vl[2][4096];     // [parity][hd64*kv64]       16KB
  const int bi = blockIdx.x;
  const int xcd = bi & 7, slot = bi >> 3;
  const int bh = xcd * 4 + (slot & 3);
  const int qt = 31 - (slot >> 2);           // 64-row supertile, heavy first
  const int t = threadIdx.x, lane = t & 63, wid = t >> 6;
  const int qw = wid & 1, pw = wid >> 1;     // q-half / staging role, kv-parity
  const int l31 = lane & 31, h = lane >> 5;
  const int h8 = h * 8, h16 = h * 16, h4 = h * 4;
  const int bb = bh >> 4, hh = bh & 15;
  const size_t base = (size_t)bh * (S_ * HD_);
  const int q0 = qt * 64 + qw * 32;          // this wave's 32 q-rows
  const float NEG = -1e30f;
  const float SCALE = 0.18033688011112042f;  // (1/8)*log2(e)
  const float FM = 10.0f;                    // fixed softmax exponent (exp2 domain)
  const int srow = lane >> 3;
  const int scol = ((lane & 7) ^ srow) << 3;

  bf16x8 qf[4];
  {
    const unsigned short* qp =
        QKVc + (size_t)(bb * S_ + q0 + l31) * QKVW + hh * 64 + h8;
#pragma unroll
    for (int ks = 0; ks < 4; ++ks) qf[ks] = *reinterpret_cast<const bf16x8*>(qp + ks * 16);
  }
  f32x16 o0 = {}, o1 = {};
  float lacc[8] = {};

#define STAGEK(buf, kvb)                                                              \
  do {                                                                                \
    _Pragma("unroll") for (int c = 0; c < 8; ++c)                                     \
      gll16(QKVc + (size_t)(bb * S_ + (kvb) + c * 8 + srow) * QKVW + 1024 +           \
                hh * 64 + scol,                                                       \
            &Kl[buf][pw][c * 8 * 64]);                                                \
  } while (0)

#define STAGEV(kvb)                                                                   \
  do {                                                                                \
    _Pragma("unroll") for (int c = 0; c < 8; ++c)                                     \
      gll16(Vt + base + (size_t)(c * 8 + srow) * S_ + (kvb) + scol,                   \
            &Vl[pw][c * 8 * 64]);                                                     \
  } while (0)

#define COMPUTE_QK(cb, tcur)                                                         \
  do {                                                                               \
    const int kv0 = (tcur) * 64;                                                     \
    const bool diag = (kv0 + 63 > q0);                                               \
    const char* kbase = (const char*)&Kl[cb][pw][0];                                 \
    const int key = (l31 & 7) << 4;                                                  \
    f32x16 s0 = {}, s1 = {};                                                         \
    __builtin_amdgcn_s_setprio(1);                                                   \
    _Pragma("unroll") for (int ks = 0; ks < 4; ++ks) {                               \
      bf16x8 ka = *(const bf16x8*)(kbase + l31 * 128 + ((ks * 32 + h16) ^ key));     \
      s0 = MFMA32(ka, qf[ks], s0);                                                   \
    }                                                                                \
    if (f2) {                                                                        \
      _Pragma("unroll") for (int ks = 0; ks < 4; ++ks) {                             \
        bf16x8 kb = *(const bf16x8*)(kbase + (32 + l31) * 128 + ((ks * 32 + h16) ^ key)); \
        s1 = MFMA32(kb, qf[ks], s1);                                                 \
      }                                                                              \
    }                                                                                \
    __builtin_amdgcn_s_setprio(0);                                                   \
    if (diag) {                                                                      \
      const int lim0 = q0 + l31 - kv0;                                               \
      const int lim1 = lim0 - 32;                                                    \
      _Pragma("unroll") for (int r = 0; r < 16; ++r) {                               \
        const int cr = (r & 3) + 8 * (r >> 2) + h4;                                  \
        if (cr > lim0) s0[r] = NEG;                                                  \
        if (f2 && cr > lim1) s1[r] = NEG;                                            \
      }                                                                              \
    }                                                                                \
    _Pragma("unroll") for (int r = 0; r < 16; ++r)                                   \
      s0[r] = exp2f(fmaf(s0[r], SCALE, -FM));                                        \
    if (f2) {                                                                        \
      _Pragma("unroll") for (int r = 0; r < 16; ++r)                                 \
        s1[r] = exp2f(fmaf(s1[r], SCALE, -FM));                                      \
    }                                                                                \
    _Pragma("unroll") for (int r = 0; r < 8; ++r) {                                  \
      float ps = s0[r] + s0[r + 8];                                                  \
      if (f2) ps += s1[r] + s1[r + 8];                                               \
      lacc[r] += ps;                                                                 \
    }                                                                                \
    {                                                                                \
      union { unsigned u[4]; bf16x8 v; } uu;                                         \
      unsigned a0, a1, a2, a3, w0, w1, w2, w3;                                       \
      w0 = pk2(s0[0], s0[1]); w1 = pk2(s0[2], s0[3]);                                \
      w2 = pk2(s0[4], s0[5]); w3 = pk2(s0[6], s0[7]);                                \
      plswap2(a0, a2, w0, w2); plswap2(a1, a3, w1, w3);                              \
      uu.u[0] = a0; uu.u[1] = a1; uu.u[2] = a2; uu.u[3] = a3; pa[0] = uu.v;          \
      w0 = pk2(s0[8], s0[9]); w1 = pk2(s0[10], s0[11]);                              \
      w2 = pk2(s0[12], s0[13]); w3 = pk2(s0[14], s0[15]);                            \
      plswap2(a0, a2, w0, w2); plswap2(a1, a3, w1, w3);                              \
      uu.u[0] = a0; uu.u[1] = a1; uu.u[2] = a2; uu.u[3] = a3; pa[1] = uu.v;          \
      if (f2) {                                                                      \
        w0 = pk2(s1[0], s1[1]); w1 = pk2(s1[2], s1[3]);                              \
        w2 = pk2(s1[4], s1[5]); w3 = pk2(s1[6], s1[7]);                              \
        plswap2(a0, a2, w0, w2); plswap2(a1, a3, w1, w3);                            \
        uu.u[0] = a0; uu.u[1] = a1; uu.u[2] = a2; uu.u[3] = a3; pa[2] = uu.v;        \
        w0 = pk2(s1[8], s1[9]); w1 = pk2(s1[10], s1[11]);                            \
        w2 = pk2(s1[12], s1[13]); w3 = pk2(s1[14], s1[15]);                          \
        plswap2(a0, a2, w0, w2); plswap2(a1, a3, w1, w3);                            \
        uu.u[0] = a0; uu.u[1] = a1; uu.u[2] = a2; uu.u[3] = a3; pa[3] = uu.v;        \
      }                                                                              \
    }                                                                                \
  } while (0)

#define COMPUTE_PV()                                                                 \
  do {                                                                               \
    const char* vbase = (const char*)&Vl[pw][0];                                     \
    const int key = (l31 & 7) << 4;                                                  \
    __builtin_amdgcn_s_setprio(1);                                                   \
    _Pragma("unroll") for (int hb = 0; hb < 2; ++hb) {                               \
      _Pragma("unroll") for (int ks = 0; ks < 4; ++ks)                               \
        if (f2 || ks < 2) {                                                          \
          bf16x8 va = *(const bf16x8*)(vbase + (hb * 32 + l31) * 128 +               \
                                       ((ks * 32 + h16) ^ key));                     \
          if (hb == 0) o0 = MFMA32(va, pa[ks], o0);                                  \
          else         o1 = MFMA32(va, pa[ks], o1);                                  \
        }                                                                            \
    }                                                                                \
    __builtin_amdgcn_s_setprio(0);                                                   \
  } while (0)

  const int npair = (qt >> 1) + 1;
  // prologue: K-stagers load pair-0 K tile (own parity, if it exists)
  if (qw == 0 && pw <= qt) STAGEK(0, pw * 64);
  for (int p = 0; p < npair; ++p) {
    const int cb = p & 1;
    const int tcur = 2 * p + pw;
    // V(t): consumed at END of this iter's chain -> latency hides under QK+softmax
    if (qw == 1 && tcur <= qt) STAGEV(tcur * 64);
    if (qw == 0) {
      if (tcur + 2 <= qt) {
        STAGEK(cb ^ 1, (tcur + 2) * 64);
        __asm__ volatile("s_waitcnt vmcnt(8)" ::: "memory");   // K(t) done, K(t+2) in flight
      } else {
        __asm__ volatile("s_waitcnt vmcnt(0)" ::: "memory");   // drain K(t)
      }
    }
    __builtin_amdgcn_s_barrier();                              // K(t) visible
    bf16x8 pa[4];
    const bool f2 = (tcur * 64 + 32 <= q0 + 31);
    if (tcur <= qt) COMPUTE_QK(cb, tcur);
    if (qw == 1) __asm__ volatile("s_waitcnt vmcnt(0)" ::: "memory");  // V(t) done
    __builtin_amdgcn_s_barrier();                              // V(t) visible
    if (tcur <= qt) COMPUTE_PV();
    __builtin_amdgcn_s_barrier();                              // buffers free for overwrite
  }

  // ---- row sums: tree + cross-half, once
  float lrow = 0.f;
#pragma unroll
  for (int r = 0; r < 8; ++r) lrow += lacc[r];
  lrow += __shfl_xor(lrow, 32);

  // ---- parity merge via LDS (exact: same fixed exponent)
  float* mb = (float*)&Kl[0][0][0];
  const int mi = qw * 2112 + lane * 33;
  if (pw == 1) {
#pragma unroll
    for (int r = 0; r < 16; ++r) { mb[mi + r] = o0[r]; mb[mi + 16 + r] = o1[r]; }
    mb[mi + 32] = lrow;
  }
  __syncthreads();
  if (pw == 1) return;
#pragma unroll
  for (int r = 0; r < 16; ++r) { o0[r] += mb[mi + r]; o1[r] += mb[mi + 16 + r]; }
  lrow += mb[mi + 32];

  // ---- epilogue: O^T -> LDS -> coalesced bf16 stores (Cxt [b,h,s,hd])
  float* obuf = (float*)&Vl[0][0] + (size_t)qw * 2048;
  const float rl = 1.0f / lrow;
#pragma unroll
  for (int r = 0; r < 16; ++r) {
    const int cr = (r & 3) + 8 * (r >> 2) + h4;
    obuf[l31 * 64 + (cr ^ ((l31 & 7) << 2))] = o0[r] * rl;
    obuf[l31 * 64 + ((32 + cr) ^ ((l31 & 7) << 2))] = o1[r] * rl;
  }
  __asm__ volatile("s_waitcnt lgkmcnt(0)" ::: "memory");
#pragma unroll
  for (int p = 0; p < 8; ++p) {
    const int r = (lane >> 4) + p * 4;
    const int ce = ((lane & 15) * 4) ^ ((r & 7) << 2);
    const f32x4 v = *reinterpret_cast<const f32x4*>(&obuf[r * 64 + ce]);
    u16x4 wv = {f2bf(v[0]), f2bf(v[1]), f2bf(v[2]), f2bf(v[3])};
    *reinterpret_cast<u16x4*>(&Cxt[base + (size_t)(q0 + r) * HD_ + (lane & 15) * 4]) = wv;
  }
}

// ---------------- Output projection: 64x128 tile, dbuf LDS (48KB -> 3 blk/CU),
// counted vmcnt, 2D XCD chunks (16m x 4n per XCD). Ctx head-blocked [b][h][s][hd].
__global__ __launch_bounds__(256) void gemm_out(
    const unsigned short* __restrict__ Cxt, const unsigned short* __restrict__ WT,
    const float* __restrict__ bias, float* __restrict__ out) {
  constexpr int NM = 1024;
  __shared__ __align__(16) unsigned short As[2][64 * 64];
  __shared__ __align__(16) unsigned short Bs[2][128 * 64];
  const int bid = blockIdx.y * 8 + blockIdx.x;           // 512 blocks
  const int xcd = bid & 7, rr = bid >> 3;                // rr 0..63
  const int m0 = ((xcd >> 1) * 16 + (rr & 15)) * 64;     // 4 m-groups of 16 panels
  const int n0 = ((xcd & 1) * 4 + (rr >> 4)) * 128;      // 2 n-groups of 4 panels
  const int t = threadIdx.x;
  const int lane = t & 63, wid = t >> 6;
  const int wr = wid >> 1, wc = wid & 1;
  const int l15 = lane & 15, l16 = lane >> 4;
  const int srow = lane >> 3, scol = ((lane & 7) ^ srow) << 3;
  f32x4 acc[2][4] = {};

#define OSTAGE(buf, k0)                                                              \
  do {                                                                               \
    const int head = (k0) >> 6;                                                      \
    _Pragma("unroll") for (int c = 0; c < 2; ++c) {                                  \
      const int r8 = wid * 16 + c * 8;                                               \
      const int gr = m0 + r8 + srow;                                                 \
      gll16(Cxt + ((((size_t)(gr >> 11) * H_ + head) << 11) + (gr & 2047)) * HD_ + scol, \
            &As[buf][r8 * 64]);                                                      \
    }                                                                                \
    _Pragma("unroll") for (int c = 0; c < 4; ++c) {                                  \
      const int r8 = wid * 32 + c * 8;                                               \
      gll16(WT + (size_t)(n0 + r8 + srow) * KDIM + (k0) + scol, &Bs[buf][r8 * 64]);  \
    }                                                                                \
  } while (0)

  OSTAGE(0, 0);
  for (int kt = 0; kt < 16; ++kt) {
    const int cur = kt & 1;
    if (kt + 1 < 16) {
      OSTAGE(cur ^ 1, (kt + 1) * 64);
      __asm__ volatile("s_waitcnt vmcnt(6)" ::: "memory");
    } else {
      __asm__ volatile("s_waitcnt vmcnt(0)" ::: "memory");
    }
    __builtin_amdgcn_s_barrier();
    const int key = (l15 & 7) << 4;
    const char* ab = (const char*)&As[cur][0] + (wr * 32 + l15) * 128;
    const char* bb = (const char*)&Bs[cur][0] + (wc * 64 + l15) * 128;
#pragma unroll
    for (int ks = 0; ks < 2; ++ks) {
      bf16x8 af[2], bfr[4];
#pragma unroll
      for (int m = 0; m < 2; ++m)
        af[m] = *(const bf16x8*)(ab + m * 2048 + ((ks * 64 + l16 * 16) ^ key));
#pragma unroll
      for (int n = 0; n < 4; ++n)
        bfr[n] = *(const bf16x8*)(bb + n * 2048 + ((ks * 64 + l16 * 16) ^ key));
#pragma unroll
      for (int m = 0; m < 2; ++m)
#pragma unroll
        for (int n = 0; n < 4; ++n)
          acc[m][n] = MFMA16(af[m], bfr[n], acc[m][n]);
    }
    __builtin_amdgcn_s_barrier();
  }
#pragma unroll
  for (int n = 0; n < 4; ++n) {
    const int col = n0 + wc * 64 + n * 16 + l15;
    const float bv = bias[col];
#pragma unroll
    for (int m = 0; m < 2; ++m) {
#pragma unroll
      for (int j = 0; j < 4; ++j) {
        const int row = m0 + wr * 32 + m * 16 + l16 * 4 + j;
        out[(size_t)row * NM + col] = acc[m][n][j] + bv;
      }
    }
  }
}

extern "C" void kernel_launch(void* const* d_in, const int* in_sizes, int n_in,
                              void* d_out, int out_size, void* d_ws, size_t ws_size,
                              hipStream_t stream) {
  const float* x = (const float*)d_in[0];
  const float* w_qkv = (const float*)d_in[1];
  const float* b_qkv = (const float*)d_in[2];
  const float* w_out = (const float*)d_in[3];
  const float* b_out = (const float*)d_in[4];
  float* out = (float*)d_out;

  const size_t NTOK = (size_t)B_ * H_ * S_ * HD_;  // 4,194,304 elements
  unsigned short* QKVc = (unsigned short*)d_ws;     // [4096][3072]
  unsigned short* Vt = QKVc + (size_t)4096 * QKVW;  // V transposed [b,h,hd,s]
  unsigned short* WqT = Vt + NTOK;                  // [3072][1024]
  unsigned short* WoT = WqT + (size_t)3072 * 1024;  // [1024][1024]
  unsigned short* Xbf = WoT + (size_t)1024 * 1024;  // [4096][1024]
  unsigned short* Cxt = Xbf;                        // alias: Xbf dead before attn writes

  hipLaunchKernelGGL(prep, dim3(2048 + 768 + 256), dim3(256), 0, stream,
                     x, Xbf, w_qkv, WqT, w_out, WoT);
  hipLaunchKernelGGL(gemm_qkv, dim3(24, 64), dim3(256), 0, stream, Xbf, WqT, b_qkv, QKVc, Vt);
  hipLaunchKernelGGL(attn, dim3(1024), dim3(256), 0, stream, QKVc, Vt, Cxt);
  hipLaunchKernelGGL(gemm_out, dim3(8, 64), dim3(256), 0, stream, Cxt, WoT, b_out, out);
}

// Round 22
// 100.590 us; speedup vs baseline: 4.0152x; 1.0010x over previous
//
#include <hip/hip_runtime.h>
#include <hip/hip_bf16.h>

#define B_ 2
#define S_ 2048
#define D_ 1024
#define H_ 16
#define HD_ 64
#define KDIM 1024
#define QKVW 3072

typedef __attribute__((ext_vector_type(8))) short s16x8;
typedef __attribute__((ext_vector_type(8))) __bf16 bf16x8;
typedef __attribute__((ext_vector_type(4))) float f32x4;
typedef __attribute__((ext_vector_type(16))) float f32x16;
typedef __attribute__((ext_vector_type(4))) unsigned short u16x4;

__device__ __forceinline__ unsigned short f2bf(float f) {
  union { __bf16 b; unsigned short u; } v;
  v.b = (__bf16)f;
  return v.u;
}

__device__ __forceinline__ unsigned pk2(float lo, float hi) {
  union { unsigned short s[2]; unsigned u; } r;
  r.s[0] = f2bf(lo); r.s[1] = f2bf(hi);
  return r.u;
}

// permlane32_swap(a, b): HW swaps a[32+j] <-> b[j].
__device__ __forceinline__ void plswap2(unsigned& a_out, unsigned& b_out,
                                        unsigned a, unsigned b) {
  auto rr = __builtin_amdgcn_permlane32_swap(a, b, false, false);
  unsigned out[2];
  __builtin_memcpy(out, &rr, 8);
  a_out = out[0];
  b_out = out[1];
}

#define MFMA16(a, b, c) __builtin_amdgcn_mfma_f32_16x16x32_bf16((a), (b), (c), 0, 0, 0)
#define MFMA32(a, b, c) __builtin_amdgcn_mfma_f32_32x32x16_bf16((a), (b), (c), 0, 0, 0)

__device__ __forceinline__ void gll16(const void* g, void* l) {
  __builtin_amdgcn_global_load_lds(
      (const __attribute__((address_space(1))) void*)g,
      (__attribute__((address_space(3))) void*)l, 16, 0, 0);
}

// ---------------- fused prep: X fp32->bf16 | w_qkv transpose | w_out transpose
__global__ __launch_bounds__(256) void prep(const float* __restrict__ X,
                                            unsigned short* __restrict__ Xb,
                                            const float* __restrict__ Wq,
                                            unsigned short* __restrict__ WqT,
                                            const float* __restrict__ Wo,
                                            unsigned short* __restrict__ WoT) {
  const int bid = blockIdx.x;
  const int t = threadIdx.x;
  if (bid < 2048) {
    const int i = (bid * 256 + t) * 8;
    const float4 a = *reinterpret_cast<const float4*>(X + i);
    const float4 b = *reinterpret_cast<const float4*>(X + i + 4);
    u16x4 lo = {f2bf(a.x), f2bf(a.y), f2bf(a.z), f2bf(a.w)};
    u16x4 hi = {f2bf(b.x), f2bf(b.y), f2bf(b.z), f2bf(b.w)};
    *reinterpret_cast<u16x4*>(Xb + i) = lo;
    *reinterpret_cast<u16x4*>(Xb + i + 4) = hi;
    return;
  }
  __shared__ float T[64][65];
  const float* W;
  unsigned short* Wt;
  int N, k0, n0;
  if (bid < 2048 + 768) {
    const int i = bid - 2048;
    W = Wq; Wt = WqT; N = 3072;
    n0 = (i % 48) * 64; k0 = (i / 48) * 64;
  } else {
    const int i = bid - 2816;
    W = Wo; Wt = WoT; N = 1024;
    n0 = (i % 16) * 64; k0 = (i / 16) * 64;
  }
  const int lr = t >> 4, lc = (t & 15) * 4;
#pragma unroll
  for (int p = 0; p < 4; ++p) {
    const int r = lr + p * 16;
    const float4 v = *reinterpret_cast<const float4*>(W + (size_t)(k0 + r) * N + n0 + lc);
    T[r][lc + 0] = v.x; T[r][lc + 1] = v.y; T[r][lc + 2] = v.z; T[r][lc + 3] = v.w;
  }
  __syncthreads();
  const int wn = t >> 4, wk = (t & 15) * 4;
#pragma unroll
  for (int p = 0; p < 4; ++p) {
    const int n = wn + p * 16;
    u16x4 o = {f2bf(T[wk + 0][n]), f2bf(T[wk + 1][n]), f2bf(T[wk + 2][n]), f2bf(T[wk + 3][n])};
    *reinterpret_cast<u16x4*>(Wt + (size_t)(n0 + n) * 1024 + k0 + wk) = o;
  }
}

// ---------------- QKV projection: 64x128 tile, dbuf LDS (48KB -> 3 blk/CU),
// counted vmcnt, 2D XCD chunks (16m x 12n per XCD).
// Q/K columns -> Cq; V columns -> Vt[b,h,hd,s] directly (LDS-transposed epilogue).
__global__ __launch_bounds__(256) void gemm_qkv(
    const unsigned short* __restrict__ Xb, const unsigned short* __restrict__ WT,
    const float* __restrict__ bias, unsigned short* __restrict__ Cq,
    unsigned short* __restrict__ Vt) {
  __shared__ __align__(16) unsigned short As[2][64 * 64];
  __shared__ __align__(16) unsigned short Bs[2][128 * 64];
  const int bid = blockIdx.y * 24 + blockIdx.x;          // 1536 blocks
  const int xcd = bid & 7, rr = bid >> 3;                // rr 0..191
  const int m0 = ((xcd >> 1) * 16 + (rr & 15)) * 64;     // 4 m-groups of 16 panels
  const int n0 = ((xcd & 1) * 12 + (rr >> 4)) * 128;     // 2 n-groups of 12 panels
  const int t = threadIdx.x;
  const int lane = t & 63, wid = t >> 6;
  const int wr = wid >> 1, wc = wid & 1;
  const int l15 = lane & 15, l16 = lane >> 4;
  const int srow = lane >> 3, scol = ((lane & 7) ^ srow) << 3;
  f32x4 acc[2][4] = {};

#define GSTAGE(buf, k0)                                                              \
  do {                                                                               \
    _Pragma("unroll") for (int c = 0; c < 2; ++c) {                                  \
      const int r8 = wid * 16 + c * 8;                                               \
      gll16(Xb + (size_t)(m0 + r8 + srow) * KDIM + (k0) + scol, &As[buf][r8 * 64]);  \
    }                                                                                \
    _Pragma("unroll") for (int c = 0; c < 4; ++c) {                                  \
      const int r8 = wid * 32 + c * 8;                                               \
      gll16(WT + (size_t)(n0 + r8 + srow) * KDIM + (k0) + scol, &Bs[buf][r8 * 64]);  \
    }                                                                                \
  } while (0)

  GSTAGE(0, 0);
  for (int kt = 0; kt < 16; ++kt) {
    const int cur = kt & 1;
    if (kt + 1 < 16) {
      GSTAGE(cur ^ 1, (kt + 1) * 64);
      __asm__ volatile("s_waitcnt vmcnt(6)" ::: "memory");  // tile kt landed; kt+1 in flight
    } else {
      __asm__ volatile("s_waitcnt vmcnt(0)" ::: "memory");
    }
    __builtin_amdgcn_s_barrier();
    const int key = (l15 & 7) << 4;
    const char* ab = (const char*)&As[cur][0] + (wr * 32 + l15) * 128;
    const char* bb = (const char*)&Bs[cur][0] + (wc * 64 + l15) * 128;
#pragma unroll
    for (int ks = 0; ks < 2; ++ks) {
      bf16x8 af[2], bfr[4];
#pragma unroll
      for (int m = 0; m < 2; ++m)
        af[m] = *(const bf16x8*)(ab + m * 2048 + ((ks * 64 + l16 * 16) ^ key));
#pragma unroll
      for (int n = 0; n < 4; ++n)
        bfr[n] = *(const bf16x8*)(bb + n * 2048 + ((ks * 64 + l16 * 16) ^ key));
#pragma unroll
      for (int m = 0; m < 2; ++m)
#pragma unroll
        for (int n = 0; n < 4; ++n)
          acc[m][n] = MFMA16(af[m], bfr[n], acc[m][n]);
    }
    __builtin_amdgcn_s_barrier();
  }
  if (n0 < 2048) {
    // Q/K columns -> plain Cq (+bias)
#pragma unroll
    for (int n = 0; n < 4; ++n) {
      const int col = n0 + wc * 64 + n * 16 + l15;
      const float bv = bias[col];
#pragma unroll
      for (int m = 0; m < 2; ++m) {
#pragma unroll
        for (int j = 0; j < 4; ++j) {
          const int row = m0 + wr * 32 + m * 16 + l16 * 4 + j;
          Cq[(size_t)row * QKVW + col] = f2bf(acc[m][n][j] + bv);
        }
      }
    }
  } else {
    // V columns -> Vt[b,h,hd,s] via LDS transpose (Bs free after final barrier)
    unsigned short* T = &Bs[0][0];  // [128][68] u16 = 17408 B
#pragma unroll
    for (int n = 0; n < 4; ++n) {
      const int col = n0 + wc * 64 + n * 16 + l15;
      const float bv = bias[col];
      const int trow = wc * 64 + n * 16 + l15;
#pragma unroll
      for (int m = 0; m < 2; ++m) {
#pragma unroll
        for (int j = 0; j < 4; ++j)
          T[trow * 68 + wr * 32 + m * 16 + l16 * 4 + j] = f2bf(acc[m][n][j] + bv);
      }
    }
    __syncthreads();
    const int bb2 = m0 >> 11, s0t = m0 & 2047;
    const int hh0 = (n0 - 2048) >> 6;
#pragma unroll
    for (int p = 0; p < 4; ++p) {
      const int idx = p * 256 + t;
      const int vd = idx >> 3, sg = (idx & 7) * 8;
      const int hd = vd & 63, hx = vd >> 6;
      *reinterpret_cast<s16x8*>(
          &Vt[(((size_t)bb2 * H_ + hh0 + hx) * HD_ + hd) * S_ + s0t + sg]) =
          *reinterpret_cast<const s16x8*>(&T[vd * 68 + sg]);
    }
  }
}

// ---------------- Flash attention: [r12/r16-proven 47us] 4-wave blocks,
// K dbuf + V single, fixed-exponent softmax, counted vmcnt.
// 1024 blocks, 4 heads/XCD, heavy-first.
__global__ __launch_bounds__(256, 3) void attn(
    const unsigned short* __restrict__ QKVc, const unsigned short* __restrict__ Vt,
    unsigned short* __restrict__ Cxt) {
  __shared__ __align__(16) unsigned short Kl[2][2][4096];  // [Kdbuf][parity][kv64*hd64] 32KB
  __shared__ __align__(16) unsigned short Vl[2][4096];     // [parity][hd64*kv64]       16KB
  const int bi = blockIdx.x;
  const int xcd = bi & 7, slot = bi >> 3;
  const int bh = xcd * 4 + (slot & 3);
  const int qt = 31 - (slot >> 2);           // 64-row supertile, heavy first
  const int t = threadIdx.x, lane = t & 63, wid = t >> 6;
  const int qw = wid & 1, pw = wid >> 1;     // q-half / staging role, kv-parity
  const int l31 = lane & 31, h = lane >> 5;
  const int h8 = h * 8, h16 = h * 16, h4 = h * 4;
  const int bb = bh >> 4, hh = bh & 15;
  const size_t base = (size_t)bh * (S_ * HD_);
  const int q0 = qt * 64 + qw * 32;          // this wave's 32 q-rows
  const float NEG = -1e30f;
  const float SCALE = 0.18033688011112042f;  // (1/8)*log2(e)
  const float FM = 10.0f;                    // fixed softmax exponent (exp2 domain)
  const int srow = lane >> 3;
  const int scol = ((lane & 7) ^ srow) << 3;

  bf16x8 qf[4];
  {
    const unsigned short* qp =
        QKVc + (size_t)(bb * S_ + q0 + l31) * QKVW + hh * 64 + h8;
#pragma unroll
    for (int ks = 0; ks < 4; ++ks) qf[ks] = *reinterpret_cast<const bf16x8*>(qp + ks * 16);
  }
  f32x16 o0 = {}, o1 = {};
  float lacc[8] = {};

#define STAGEK(buf, kvb)                                                              \
  do {                                                                                \
    _Pragma("unroll") for (int c = 0; c < 8; ++c)                                     \
      gll16(QKVc + (size_t)(bb * S_ + (kvb) + c * 8 + srow) * QKVW + 1024 +           \
                hh * 64 + scol,                                                       \
            &Kl[buf][pw][c * 8 * 64]);                                                \
  } while (0)

#define STAGEV(kvb)                                                                   \
  do {                                                                                \
    _Pragma("unroll") for (int c = 0; c < 8; ++c)                                     \
      gll16(Vt + base + (size_t)(c * 8 + srow) * S_ + (kvb) + scol,                   \
            &Vl[pw][c * 8 * 64]);                                                     \
  } while (0)

#define COMPUTE_QK(cb, tcur)                                                         \
  do {                                                                               \
    const int kv0 = (tcur) * 64;                                                     \
    const bool diag = (kv0 + 63 > q0);                                               \
    const char* kbase = (const char*)&Kl[cb][pw][0];                                 \
    const int key = (l31 & 7) << 4;                                                  \
    f32x16 s0 = {}, s1 = {};                                                         \
    __builtin_amdgcn_s_setprio(1);                                                   \
    _Pragma("unroll") for (int ks = 0; ks < 4; ++ks) {                               \
      bf16x8 ka = *(const bf16x8*)(kbase + l31 * 128 + ((ks * 32 + h16) ^ key));     \
      s0 = MFMA32(ka, qf[ks], s0);                                                   \
    }                                                                                \
    if (f2) {                                                                        \
      _Pragma("unroll") for (int ks = 0; ks < 4; ++ks) {                             \
        bf16x8 kb = *(const bf16x8*)(kbase + (32 + l31) * 128 + ((ks * 32 + h16) ^ key)); \
        s1 = MFMA32(kb, qf[ks], s1);                                                 \
      }                                                                              \
    }                                                                                \
    __builtin_amdgcn_s_setprio(0);                                                   \
    if (diag) {                                                                      \
      const int lim0 = q0 + l31 - kv0;                                               \
      const int lim1 = lim0 - 32;                                                    \
      _Pragma("unroll") for (int r = 0; r < 16; ++r) {                               \
        const int cr = (r & 3) + 8 * (r >> 2) + h4;                                  \
        if (cr > lim0) s0[r] = NEG;                                                  \
        if (f2 && cr > lim1) s1[r] = NEG;                                            \
      }                                                                              \
    }                                                                                \
    _Pragma("unroll") for (int r = 0; r < 16; ++r)                                   \
      s0[r] = exp2f(fmaf(s0[r], SCALE, -FM));                                        \
    if (f2) {                                                                        \
      _Pragma("unroll") for (int r = 0; r < 16; ++r)                                 \
        s1[r] = exp2f(fmaf(s1[r], SCALE, -FM));                                      \
    }                                                                                \
    _Pragma("unroll") for (int r = 0; r < 8; ++r) {                                  \
      float ps = s0[r] + s0[r + 8];                                                  \
      if (f2) ps += s1[r] + s1[r + 8];                                               \
      lacc[r] += ps;                                                                 \
    }                                                                                \
    {                                                                                \
      union { unsigned u[4]; bf16x8 v; } uu;                                         \
      unsigned a0, a1, a2, a3, w0, w1, w2, w3;                                       \
      w0 = pk2(s0[0], s0[1]); w1 = pk2(s0[2], s0[3]);                                \
      w2 = pk2(s0[4], s0[5]); w3 = pk2(s0[6], s0[7]);                                \
      plswap2(a0, a2, w0, w2); plswap2(a1, a3, w1, w3);                              \
      uu.u[0] = a0; uu.u[1] = a1; uu.u[2] = a2; uu.u[3] = a3; pa[0] = uu.v;          \
      w0 = pk2(s0[8], s0[9]); w1 = pk2(s0[10], s0[11]);                              \
      w2 = pk2(s0[12], s0[13]); w3 = pk2(s0[14], s0[15]);                            \
      plswap2(a0, a2, w0, w2); plswap2(a1, a3, w1, w3);                              \
      uu.u[0] = a0; uu.u[1] = a1; uu.u[2] = a2; uu.u[3] = a3; pa[1] = uu.v;          \
      if (f2) {                                                                      \
        w0 = pk2(s1[0], s1[1]); w1 = pk2(s1[2], s1[3]);                              \
        w2 = pk2(s1[4], s1[5]); w3 = pk2(s1[6], s1[7]);                              \
        plswap2(a0, a2, w0, w2); plswap2(a1, a3, w1, w3);                            \
        uu.u[0] = a0; uu.u[1] = a1; uu.u[2] = a2; uu.u[3] = a3; pa[2] = uu.v;        \
        w0 = pk2(s1[8], s1[9]); w1 = pk2(s1[10], s1[11]);                            \
        w2 = pk2(s1[12], s1[13]); w3 = pk2(s1[14], s1[15]);                          \
        plswap2(a0, a2, w0, w2); plswap2(a1, a3, w1, w3);                            \
        uu.u[0] = a0; uu.u[1] = a1; uu.u[2] = a2; uu.u[3] = a3; pa[3] = uu.v;        \
      }                                                                              \
    }                                                                                \
  } while (0)

#define COMPUTE_PV()                                                                 \
  do {                                                                               \
    const char* vbase = (const char*)&Vl[pw][0];                                     \
    const int key = (l31 & 7) << 4;                                                  \
    __builtin_amdgcn_s_setprio(1);                                                   \
    _Pragma("unroll") for (int hb = 0; hb < 2; ++hb) {                               \
      _Pragma("unroll") for (int ks = 0; ks < 4; ++ks)                               \
        if (f2 || ks < 2) {                                                          \
          bf16x8 va = *(const bf16x8*)(vbase + (hb * 32 + l31) * 128 +               \
                                       ((ks * 32 + h16) ^ key));                     \
          if (hb == 0) o0 = MFMA32(va, pa[ks], o0);                                  \
          else         o1 = MFMA32(va, pa[ks], o1);                                  \
        }                                                                            \
    }                                                                                \
    __builtin_amdgcn_s_setprio(0);                                                   \
  } while (0)

  const int npair = (qt >> 1) + 1;
  // prologue: K-stagers load pair-0 K tile (own parity, if it exists)
  if (qw == 0 && pw <= qt) STAGEK(0, pw * 64);
  for (int p = 0; p < npair; ++p) {
    const int cb = p & 1;
    const int tcur = 2 * p + pw;
    // V(t): consumed at END of this iter's chain -> latency hides under QK+softmax
    if (qw == 1 && tcur <= qt) STAGEV(tcur * 64);
    if (qw == 0) {
      if (tcur + 2 <= qt) {
        STAGEK(cb ^ 1, (tcur + 2) * 64);
        __asm__ volatile("s_waitcnt vmcnt(8)" ::: "memory");   // K(t) done, K(t+2) in flight
      } else {
        __asm__ volatile("s_waitcnt vmcnt(0)" ::: "memory");   // drain K(t)
      }
    }
    __builtin_amdgcn_s_barrier();                              // K(t) visible
    bf16x8 pa[4];
    const bool f2 = (tcur * 64 + 32 <= q0 + 31);
    if (tcur <= qt) COMPUTE_QK(cb, tcur);
    if (qw == 1) __asm__ volatile("s_waitcnt vmcnt(0)" ::: "memory");  // V(t) done
    __builtin_amdgcn_s_barrier();                              // V(t) visible
    if (tcur <= qt) COMPUTE_PV();
    __builtin_amdgcn_s_barrier();                              // buffers free for overwrite
  }

  // ---- row sums: tree + cross-half, once
  float lrow = 0.f;
#pragma unroll
  for (int r = 0; r < 8; ++r) lrow += lacc[r];
  lrow += __shfl_xor(lrow, 32);

  // ---- parity merge via LDS (exact: same fixed exponent)
  float* mb = (float*)&Kl[0][0][0];
  const int mi = qw * 2112 + lane * 33;
  if (pw == 1) {
#pragma unroll
    for (int r = 0; r < 16; ++r) { mb[mi + r] = o0[r]; mb[mi + 16 + r] = o1[r]; }
    mb[mi + 32] = lrow;
  }
  __syncthreads();
  if (pw == 1) return;
#pragma unroll
  for (int r = 0; r < 16; ++r) { o0[r] += mb[mi + r]; o1[r] += mb[mi + 16 + r]; }
  lrow += mb[mi + 32];

  // ---- epilogue: O^T -> LDS -> coalesced bf16 stores (Cxt [b,h,s,hd])
  float* obuf = (float*)&Vl[0][0] + (size_t)qw * 2048;
  const float rl = 1.0f / lrow;
#pragma unroll
  for (int r = 0; r < 16; ++r) {
    const int cr = (r & 3) + 8 * (r >> 2) + h4;
    obuf[l31 * 64 + (cr ^ ((l31 & 7) << 2))] = o0[r] * rl;
    obuf[l31 * 64 + ((32 + cr) ^ ((l31 & 7) << 2))] = o1[r] * rl;
  }
  __asm__ volatile("s_waitcnt lgkmcnt(0)" ::: "memory");
#pragma unroll
  for (int p = 0; p < 8; ++p) {
    const int r = (lane >> 4) + p * 4;
    const int ce = ((lane & 15) * 4) ^ ((r & 7) << 2);
    const f32x4 v = *reinterpret_cast<const f32x4*>(&obuf[r * 64 + ce]);
    u16x4 wv = {f2bf(v[0]), f2bf(v[1]), f2bf(v[2]), f2bf(v[3])};
    *reinterpret_cast<u16x4*>(&Cxt[base + (size_t)(q0 + r) * HD_ + (lane & 15) * 4]) = wv;
  }
}

// ---------------- Output projection: 64x128 tile, dbuf LDS (48KB -> 3 blk/CU),
// counted vmcnt, 2D XCD chunks (16m x 4n per XCD). Ctx head-blocked [b][h][s][hd].
__global__ __launch_bounds__(256) void gemm_out(
    const unsigned short* __restrict__ Cxt, const unsigned short* __restrict__ WT,
    const float* __restrict__ bias, float* __restrict__ out) {
  constexpr int NM = 1024;
  __shared__ __align__(16) unsigned short As[2][64 * 64];
  __shared__ __align__(16) unsigned short Bs[2][128 * 64];
  const int bid = blockIdx.y * 8 + blockIdx.x;           // 512 blocks
  const int xcd = bid & 7, rr = bid >> 3;                // rr 0..63
  const int m0 = ((xcd >> 1) * 16 + (rr & 15)) * 64;     // 4 m-groups of 16 panels
  const int n0 = ((xcd & 1) * 4 + (rr >> 4)) * 128;      // 2 n-groups of 4 panels
  const int t = threadIdx.x;
  const int lane = t & 63, wid = t >> 6;
  const int wr = wid >> 1, wc = wid & 1;
  const int l15 = lane & 15, l16 = lane >> 4;
  const int srow = lane >> 3, scol = ((lane & 7) ^ srow) << 3;
  f32x4 acc[2][4] = {};

#define OSTAGE(buf, k0)                                                              \
  do {                                                                               \
    const int head = (k0) >> 6;                                                      \
    _Pragma("unroll") for (int c = 0; c < 2; ++c) {                                  \
      const int r8 = wid * 16 + c * 8;                                               \
      const int gr = m0 + r8 + srow;                                                 \
      gll16(Cxt + ((((size_t)(gr >> 11) * H_ + head) << 11) + (gr & 2047)) * HD_ + scol, \
            &As[buf][r8 * 64]);                                                      \
    }                                                                                \
    _Pragma("unroll") for (int c = 0; c < 4; ++c) {                                  \
      const int r8 = wid * 32 + c * 8;                                               \
      gll16(WT + (size_t)(n0 + r8 + srow) * KDIM + (k0) + scol, &Bs[buf][r8 * 64]);  \
    }                                                                                \
  } while (0)

  OSTAGE(0, 0);
  for (int kt = 0; kt < 16; ++kt) {
    const int cur = kt & 1;
    if (kt + 1 < 16) {
      OSTAGE(cur ^ 1, (kt + 1) * 64);
      __asm__ volatile("s_waitcnt vmcnt(6)" ::: "memory");
    } else {
      __asm__ volatile("s_waitcnt vmcnt(0)" ::: "memory");
    }
    __builtin_amdgcn_s_barrier();
    const int key = (l15 & 7) << 4;
    const char* ab = (const char*)&As[cur][0] + (wr * 32 + l15) * 128;
    const char* bb = (const char*)&Bs[cur][0] + (wc * 64 + l15) * 128;
#pragma unroll
    for (int ks = 0; ks < 2; ++ks) {
      bf16x8 af[2], bfr[4];
#pragma unroll
      for (int m = 0; m < 2; ++m)
        af[m] = *(const bf16x8*)(ab + m * 2048 + ((ks * 64 + l16 * 16) ^ key));
#pragma unroll
      for (int n = 0; n < 4; ++n)
        bfr[n] = *(const bf16x8*)(bb + n * 2048 + ((ks * 64 + l16 * 16) ^ key));
#pragma unroll
      for (int m = 0; m < 2; ++m)
#pragma unroll
        for (int n = 0; n < 4; ++n)
          acc[m][n] = MFMA16(af[m], bfr[n], acc[m][n]);
    }
    __builtin_amdgcn_s_barrier();
  }
#pragma unroll
  for (int n = 0; n < 4; ++n) {
    const int col = n0 + wc * 64 + n * 16 + l15;
    const float bv = bias[col];
#pragma unroll
    for (int m = 0; m < 2; ++m) {
#pragma unroll
      for (int j = 0; j < 4; ++j) {
        const int row = m0 + wr * 32 + m * 16 + l16 * 4 + j;
        out[(size_t)row * NM + col] = acc[m][n][j] + bv;
      }
    }
  }
}

extern "C" void kernel_launch(void* const* d_in, const int* in_sizes, int n_in,
                              void* d_out, int out_size, void* d_ws, size_t ws_size,
                              hipStream_t stream) {
  const float* x = (const float*)d_in[0];
  const float* w_qkv = (const float*)d_in[1];
  const float* b_qkv = (const float*)d_in[2];
  const float* w_out = (const float*)d_in[3];
  const float* b_out = (const float*)d_in[4];
  float* out = (float*)d_out;

  const size_t NTOK = (size_t)B_ * H_ * S_ * HD_;  // 4,194,304 elements
  unsigned short* QKVc = (unsigned short*)d_ws;     // [4096][3072]
  unsigned short* Vt = QKVc + (size_t)4096 * QKVW;  // V transposed [b,h,hd,s]
  unsigned short* WqT = Vt + NTOK;                  // [3072][1024]
  unsigned short* WoT = WqT + (size_t)3072 * 1024;  // [1024][1024]
  unsigned short* Xbf = WoT + (size_t)1024 * 1024;  // [4096][1024]
  unsigned short* Cxt = Xbf;                        // alias: Xbf dead before attn writes

  hipLaunchKernelGGL(prep, dim3(2048 + 768 + 256), dim3(256), 0, stream,
                     x, Xbf, w_qkv, WqT, w_out, WoT);
  hipLaunchKernelGGL(gemm_qkv, dim3(24, 64), dim3(256), 0, stream, Xbf, WqT, b_qkv, QKVc, Vt);
  hipLaunchKernelGGL(attn, dim3(1024), dim3(256), 0, stream, QKVc, Vt, Cxt);
  hipLaunchKernelGGL(gemm_out, dim3(8, 64), dim3(256), 0, stream, Cxt, WoT, b_out, out);
}